// Round 4
// baseline (442.523 us; speedup 1.0000x reference)
//
#include <hip/hip_runtime.h>
#include <cmath>

using f16   = _Float16;
using f16x4 = __attribute__((ext_vector_type(4))) _Float16;
using f16x8 = __attribute__((ext_vector_type(8))) _Float16;
using f32x4 = __attribute__((ext_vector_type(4))) float;

#define DEV __device__ __forceinline__

// ---- constants ----
constexpr int Bb  = 8;
constexpr int Nn  = 1024;
constexpr int DIM = 1024;
constexpr int Hh  = 16;
constexpr int DH  = 64;
constexpr int EQKV = 3072;   // q(1024) | k(1024) | v(1024)

DEV void async16(const f16* g, f16* l) {
  __builtin_amdgcn_global_load_lds(
      (const __attribute__((address_space(1))) void*)g,
      (__attribute__((address_space(3))) void*)l, 16, 0, 0);
}

DEV float softplusf(float x) {
  // stable: max(x,0) + log1p(exp(-|x|))
  return fmaxf(x, 0.f) + log1pf(__expf(-fabsf(x)));
}

// DPP rotate-reduce over 16-lane rows (banks/rows all enabled).
template <int CTRL>
DEV float dpp_mov(float x) {
  return __builtin_bit_cast(float,
      __builtin_amdgcn_update_dpp(__builtin_bit_cast(int, x), __builtin_bit_cast(int, x),
                                  CTRL, 0xf, 0xf, false));
}
DEV float rmax16(float x) {
  x = fmaxf(x, dpp_mov<0x121>(x));  // row_ror:1
  x = fmaxf(x, dpp_mov<0x122>(x));  // row_ror:2
  x = fmaxf(x, dpp_mov<0x124>(x));  // row_ror:4
  x = fmaxf(x, dpp_mov<0x128>(x));  // row_ror:8
  return x;
}
DEV float rsum16(float x) {
  x += dpp_mov<0x121>(x);
  x += dpp_mov<0x122>(x);
  x += dpp_mov<0x124>(x);
  x += dpp_mov<0x128>(x);
  return x;
}

// ---------------- transpose + fp32->fp16 convert: dst[c][r] = src[r][c] ----------------
__global__ __launch_bounds__(256) void transpose_cvt(const float* __restrict__ src,
                                                     f16* __restrict__ dst,
                                                     int rows, int cols) {
  __shared__ float tile[32][33];
  int t = threadIdx.x, tx = t & 31, ty = t >> 5;
  int c0 = blockIdx.x * 32, r0 = blockIdx.y * 32;
#pragma unroll
  for (int j = 0; j < 32; j += 8)
    tile[ty + j][tx] = src[(size_t)(r0 + ty + j) * cols + c0 + tx];
  __syncthreads();
#pragma unroll
  for (int j = 0; j < 32; j += 8)
    dst[(size_t)(c0 + ty + j) * rows + r0 + tx] = (f16)tile[tx][ty + j];
}

// ---------------- LayerNorm (fp32 in, fp16 out) ----------------
__global__ __launch_bounds__(256) void ln_kernel(const float* __restrict__ x,
                                                 const float* __restrict__ gamma,
                                                 const float* __restrict__ beta,
                                                 f16* __restrict__ xn) {
  int row = blockIdx.x;
  int t = threadIdx.x;
  const float4* xr = (const float4*)(x + (size_t)row * DIM);
  float4 v = xr[t];
  float s  = v.x + v.y + v.z + v.w;
  float s2 = v.x * v.x + v.y * v.y + v.z * v.z + v.w * v.w;
#pragma unroll
  for (int off = 32; off; off >>= 1) {
    s  += __shfl_xor(s,  off, 64);
    s2 += __shfl_xor(s2, off, 64);
  }
  __shared__ float red[8];
  int wv = t >> 6, lane = t & 63;
  if (lane == 0) { red[wv] = s; red[4 + wv] = s2; }
  __syncthreads();
  s  = red[0] + red[1] + red[2] + red[3];
  s2 = red[4] + red[5] + red[6] + red[7];
  float mu  = s * (1.f / DIM);
  float var = s2 * (1.f / DIM) - mu * mu;
  float rs  = rsqrtf(var + 1e-5f);
  float4 g = ((const float4*)gamma)[t];
  float4 bb = ((const float4*)beta)[t];
  f16x4 o;
  o[0] = (f16)((v.x - mu) * rs * g.x + bb.x);
  o[1] = (f16)((v.y - mu) * rs * g.y + bb.y);
  o[2] = (f16)((v.z - mu) * rs * g.z + bb.z);
  o[3] = (f16)((v.w - mu) * rs * g.w + bb.w);
  ((f16x4*)(xn + (size_t)row * DIM))[t] = o;
}

// ---------------- m97-style GEMM: C[M,E] = A[M,K] * Bt[E,K]^T (out-proj) ----------------
template <bool FP32OUT>
__global__ __launch_bounds__(256) void gemm_bt(const f16* __restrict__ A,
                                               const f16* __restrict__ Bt,
                                               void* __restrict__ Cv,
                                               const float* __restrict__ bias,
                                               int M, int K, int E) {
  __shared__ f16 lA[128 * 32];
  __shared__ f16 lB[128 * 32];
  int tid  = threadIdx.x;
  int lane = tid & 63;
  int wv   = __builtin_amdgcn_readfirstlane(tid >> 6);
  int nbe  = E >> 7;
  int bm = blockIdx.x / nbe, be = blockIdx.x % nbe;
  size_t m0 = (size_t)bm * 128, e0 = (size_t)be * 128;
  int wm = (wv & 1) * 64, we = (wv >> 1) * 64;
  int lm = lane & 15, q = lane >> 4;

  f32x4 acc[4][4] = {};

  int row_s[2], cg_s[2];
#pragma unroll
  for (int r = 0; r < 2; ++r) {
    int s = r * 256 + tid;
    row_s[r] = s >> 2;
    cg_s[r]  = (s & 3) ^ ((row_s[r] >> 1) & 3);
  }
  const f16* pa[4];
  const f16* pb[4];
#pragma unroll
  for (int i = 0; i < 4; ++i) {
    int ra = wm + i * 16 + lm;
    pa[i] = lA + ra * 32 + (q ^ ((ra >> 1) & 3)) * 8;
    int rb = we + i * 16 + lm;
    pb[i] = lB + rb * 32 + (q ^ ((rb >> 1) & 3)) * 8;
  }

  for (int k0 = 0; k0 < K; k0 += 32) {
#pragma unroll
    for (int r = 0; r < 2; ++r) {
      const f16* ga = A  + (m0 + row_s[r]) * K + k0 + cg_s[r] * 8;
      const f16* gb = Bt + (e0 + row_s[r]) * K + k0 + cg_s[r] * 8;
      async16(ga, lA + (r * 256 + wv * 64) * 8);
      async16(gb, lB + (r * 256 + wv * 64) * 8);
    }
    __syncthreads();
    f16x8 af[4], bf[4];
#pragma unroll
    for (int i = 0; i < 4; ++i) {
      af[i] = *(const f16x8*)pa[i];
      bf[i] = *(const f16x8*)pb[i];
    }
#pragma unroll
    for (int i = 0; i < 4; ++i)
#pragma unroll
      for (int j = 0; j < 4; ++j)
        acc[i][j] = __builtin_amdgcn_mfma_f32_16x16x32_f16(af[i], bf[j], acc[i][j], 0, 0, 0);
    __syncthreads();
  }

#pragma unroll
  for (int i = 0; i < 4; ++i) {
    size_t mbase = m0 + wm + i * 16 + q * 4;
#pragma unroll
    for (int j = 0; j < 4; ++j) {
      size_t e = e0 + we + j * 16 + lm;
#pragma unroll
      for (int g = 0; g < 4; ++g) {
        float val = acc[i][j][g];
        if (FP32OUT)
          ((float*)Cv)[(mbase + g) * (size_t)E + e] = val + bias[e];
        else
          ((f16*)Cv)[(mbase + g) * (size_t)E + e] = (f16)val;
      }
    }
  }
}

// ---------------- QKV GEMM with fused polar epilogue ----------------
// Same K-loop as gemm_bt; epilogue applies softplus/sincos and writes directly to
// Qp[bh][n][128] (scale folded), Kp[bh][n][128], Vt[bh][d][n].  Class (q/k/v) is
// block-uniform because E-class boundaries (1024,2048) are multiples of 128.
__global__ __launch_bounds__(256) void gemm_qkv_polar(const f16* __restrict__ A,
                                                      const f16* __restrict__ Bt,
                                                      const float* __restrict__ freqs,
                                                      const float* __restrict__ fbias,
                                                      f16* __restrict__ Qp,
                                                      f16* __restrict__ Kp,
                                                      f16* __restrict__ Vt) {
  constexpr int K = DIM, E = EQKV;
  __shared__ f16 lA[128 * 32];
  __shared__ f16 lB[128 * 32];
  int tid  = threadIdx.x;
  int lane = tid & 63;
  int wv   = __builtin_amdgcn_readfirstlane(tid >> 6);
  int nbe  = E >> 7;
  int bm = blockIdx.x / nbe, be = blockIdx.x % nbe;
  size_t m0 = (size_t)bm * 128, e0 = (size_t)be * 128;
  int wm = (wv & 1) * 64, we = (wv >> 1) * 64;
  int lm = lane & 15, q = lane >> 4;

  f32x4 acc[4][4] = {};

  int row_s[2], cg_s[2];
#pragma unroll
  for (int r = 0; r < 2; ++r) {
    int s = r * 256 + tid;
    row_s[r] = s >> 2;
    cg_s[r]  = (s & 3) ^ ((row_s[r] >> 1) & 3);
  }
  const f16* pa[4];
  const f16* pb[4];
#pragma unroll
  for (int i = 0; i < 4; ++i) {
    int ra = wm + i * 16 + lm;
    pa[i] = lA + ra * 32 + (q ^ ((ra >> 1) & 3)) * 8;
    int rb = we + i * 16 + lm;
    pb[i] = lB + rb * 32 + (q ^ ((rb >> 1) & 3)) * 8;
  }

  for (int k0 = 0; k0 < K; k0 += 32) {
#pragma unroll
    for (int r = 0; r < 2; ++r) {
      const f16* ga = A  + (m0 + row_s[r]) * K + k0 + cg_s[r] * 8;
      const f16* gb = Bt + (e0 + row_s[r]) * K + k0 + cg_s[r] * 8;
      async16(ga, lA + (r * 256 + wv * 64) * 8);
      async16(gb, lB + (r * 256 + wv * 64) * 8);
    }
    __syncthreads();
    f16x8 af[4], bf[4];
#pragma unroll
    for (int i = 0; i < 4; ++i) {
      af[i] = *(const f16x8*)pa[i];
      bf[i] = *(const f16x8*)pb[i];
    }
#pragma unroll
    for (int i = 0; i < 4; ++i)
#pragma unroll
      for (int j = 0; j < 4; ++j)
        acc[i][j] = __builtin_amdgcn_mfma_f32_16x16x32_f16(af[i], bf[j], acc[i][j], 0, 0, 0);
    __syncthreads();
  }

  int cls = (int)(e0 >> 10);  // 0=q, 1=k, 2=v (block-uniform)
#pragma unroll
  for (int i = 0; i < 4; ++i) {
    int mbase = (int)m0 + wm + i * 16 + q * 4;
#pragma unroll
    for (int j = 0; j < 4; ++j) {
      int e = (int)e0 + we + j * 16 + lm;
      int h = (e >> 6) & 15, d = e & 63;
#pragma unroll
      for (int g = 0; g < 4; ++g) {
        int token = mbase + g;
        int n = token & 1023, b = token >> 10;
        int bh = b * 16 + h;
        float val = acc[i][j][g];
        if (cls == 2) {
          Vt[((size_t)bh * 64 + d) * Nn + n] = (f16)val;
        } else {
          int fidx = n * 64 + d;
          float f = freqs[fidx];
          float sp;
          if (cls == 0) {
            sp = softplusf(val) * 0.125f;  // DH^-0.5 folded into Q
          } else {
            f += fbias[fidx];
            sp = softplusf(val);
          }
          float sn, cs;
          __sincosf(f, &sn, &cs);
          f16* dstp = (cls == 0 ? Qp : Kp) + ((size_t)bh * Nn + n) * 128 + d;
          dstp[0]  = (f16)(sp * cs);
          dstp[64] = (f16)(sp * sn);
        }
      }
    }
  }
}

// ---------------- flash attention v2: 512 thr / 8 waves, q-tile 256, reg-resident Q ----
// LDS (halfs, 64 KB total): K0[0,8192) K1[8192,16384) V0[16384,20480) V1[20480,24576)
//                           P [24576 + wv*1024, +1024)  (per-wave 32x32 scratch)
// DPP rotate-reduce softmax; PV in two 32-key halves through the small P buffer.
constexpr int AK0 = 0;
constexpr int AK1 = 8192;
constexpr int AV0 = 16384;
constexpr int AV1 = 20480;
constexpr int APB = 24576;

__global__ __launch_bounds__(512, 4) void attn_kernel(const f16* __restrict__ Qp,
                                                      const f16* __restrict__ Kp,
                                                      const f16* __restrict__ Vt,
                                                      f16* __restrict__ attout) {
  __shared__ f16 smem[32768];  // 64 KB

  int tid = threadIdx.x, lane = tid & 63;
  int wv = __builtin_amdgcn_readfirstlane(tid >> 6);  // 0..7
  int lm = lane & 15, q = lane >> 4;
  int bx = blockIdx.x;
  int bh = (bx & 7) | ((bx >> 5) << 3);  // XCD swizzle: same head -> same bx%8
  int qt = (bx >> 3) & 3;                // 4 q-tiles of 256 rows
  const f16* Kbase = Kp + (size_t)bh * Nn * 128;
  const f16* Vbase = Vt + (size_t)bh * 64 * Nn;

  // ---- prologue: issue K/V tile 0 DMA first ----
#pragma unroll
  for (int i = 0; i < 2; ++i) {
    int s = i * 512 + tid;
    int r = s >> 4, c = s & 15;
    int g = c ^ (r & 15);
    async16(Kbase + (size_t)r * 128 + g * 8, smem + AK0 + (i * 512 + wv * 64) * 8);
  }
  {
    int r = tid >> 3, c = tid & 7;
    int g = c ^ (r & 7);
    async16(Vbase + (size_t)r * Nn + g * 8, smem + AV0 + (wv * 64) * 8);
  }

  // ---- Q fragments straight from global into registers (one-time) ----
  f16x8 qf[2][4];
  {
    const f16* Qb = Qp + ((size_t)bh * Nn + qt * 256 + wv * 32) * 128;
#pragma unroll
    for (int mt = 0; mt < 2; ++mt)
#pragma unroll
      for (int ks = 0; ks < 4; ++ks)
        qf[mt][ks] = *(const f16x8*)(Qb + (size_t)(mt * 16 + lm) * 128 + ks * 32 + q * 8);
  }

  f32x4 O[2][4] = {};
  float mrow[2][4], lrow[2][4];
#pragma unroll
  for (int i = 0; i < 2; ++i)
#pragma unroll
    for (int g = 0; g < 4; ++g) { mrow[i][g] = -INFINITY; lrow[i][g] = 0.f; }
  f16* sP = smem + APB + wv * 1024;  // wave-private 32x32

  for (int kt = 0; kt < 16; ++kt) {
    __syncthreads();  // tile kt ready (DMA issued a full compute-phase ago)

    // ---- prefetch tile kt+1 into the other buffer ----
    if (kt < 15) {
      f16* nK = smem + ((kt & 1) ? AK0 : AK1);
      f16* nV = smem + ((kt & 1) ? AV0 : AV1);
#pragma unroll
      for (int i = 0; i < 2; ++i) {
        int s = i * 512 + tid;
        int r = s >> 4, c = s & 15;
        int g = c ^ (r & 15);
        async16(Kbase + (size_t)((kt + 1) * 64 + r) * 128 + g * 8, nK + (i * 512 + wv * 64) * 8);
      }
      {
        int r = tid >> 3, c = tid & 7;
        int g = c ^ (r & 7);
        async16(Vbase + (size_t)r * Nn + (kt + 1) * 64 + g * 8, nV + (wv * 64) * 8);
      }
    }

    const f16* sK = smem + ((kt & 1) ? AK1 : AK0);
    const f16* sV = smem + ((kt & 1) ? AV1 : AV0);

    // ---- S = Qp * Kp^T ----
    f32x4 S[2][4] = {};
#pragma unroll
    for (int nt = 0; nt < 4; ++nt) {
      f16x8 kf[4];
#pragma unroll
      for (int ks = 0; ks < 4; ++ks)
        kf[ks] = *(const f16x8*)(sK + (nt * 16 + lm) * 128 + (((ks * 4 + q) ^ lm) * 8));
#pragma unroll
      for (int mt = 0; mt < 2; ++mt)
#pragma unroll
        for (int ks = 0; ks < 4; ++ks)
          S[mt][nt] = __builtin_amdgcn_mfma_f32_16x16x32_f16(qf[mt][ks], kf[ks], S[mt][nt], 0, 0, 0);
    }

    // ---- online softmax (DPP rotate-reduce over the 16-lane row group) ----
#pragma unroll
    for (int mt = 0; mt < 2; ++mt) {
#pragma unroll
      for (int g = 0; g < 4; ++g) {
        float mx = fmaxf(fmaxf(S[mt][0][g], S[mt][1][g]), fmaxf(S[mt][2][g], S[mt][3][g]));
        mx = rmax16(mx);
        float mn = fmaxf(mrow[mt][g], mx);
        float alpha = __expf(mrow[mt][g] - mn);
        mrow[mt][g] = mn;
        float rs = 0.f;
#pragma unroll
        for (int nt = 0; nt < 4; ++nt) {
          float p = __expf(S[mt][nt][g] - mn);
          S[mt][nt][g] = p;
          rs += p;
        }
        rs = rsum16(rs);
        lrow[mt][g] = lrow[mt][g] * alpha + rs;
#pragma unroll
        for (int nt = 0; nt < 4; ++nt) O[mt][nt][g] *= alpha;
      }
    }

    // ---- PV in two 32-key halves via the small wave-private P buffer ----
    // P swizzle: element (rl, col) at rl*32 + (((col>>3) ^ ((rl>>2)&3))*8) + (col&7)
#pragma unroll
    for (int half = 0; half < 2; ++half) {
      __asm__ __volatile__("" ::: "memory");
#pragma unroll
      for (int mt = 0; mt < 2; ++mt)
#pragma unroll
        for (int ntl = 0; ntl < 2; ++ntl) {
          int nt = half * 2 + ntl;
#pragma unroll
          for (int g = 0; g < 4; ++g) {
            int rl = mt * 16 + q * 4 + g;
            int ch = (ntl * 2 + (lm >> 3)) ^ ((rl >> 2) & 3);
            sP[rl * 32 + ch * 8 + (lm & 7)] = (f16)S[mt][nt][g];
          }
        }
      __asm__ __volatile__("" ::: "memory");
      f16x8 pf[2];
#pragma unroll
      for (int mt = 0; mt < 2; ++mt) {
        int row = mt * 16 + lm;
        pf[mt] = *(const f16x8*)(sP + row * 32 + ((q ^ ((row >> 2) & 3)) * 8));
      }
#pragma unroll
      for (int nto = 0; nto < 4; ++nto) {
        int row = nto * 16 + lm;
        f16x8 vf = *(const f16x8*)(sV + row * 64 + (((half * 4 + q) ^ (row & 7)) * 8));
#pragma unroll
        for (int mt = 0; mt < 2; ++mt)
          O[mt][nto] = __builtin_amdgcn_mfma_f32_16x16x32_f16(pf[mt], vf, O[mt][nto], 0, 0, 0);
      }
    }
  }

  // ---- epilogue ----
  int b = bh >> 4, h = bh & 15;
  size_t tok0 = (size_t)b * Nn + qt * 256;
#pragma unroll
  for (int mt = 0; mt < 2; ++mt) {
#pragma unroll
    for (int g = 0; g < 4; ++g) {
      int rloc = wv * 32 + mt * 16 + q * 4 + g;
      size_t token = tok0 + rloc;
      float inv = 1.f / lrow[mt][g];
#pragma unroll
      for (int nto = 0; nto < 4; ++nto)
        attout[token * (size_t)(Hh * DH) + h * 64 + nto * 16 + lm] =
            (f16)(O[mt][nto][g] * inv);
    }
  }
}

// ---------------- launch ----------------
extern "C" void kernel_launch(void* const* d_in, const int* in_sizes, int n_in,
                              void* d_out, int out_size, void* d_ws, size_t ws_size,
                              hipStream_t stream) {
  const float* x     = (const float*)d_in[0];
  const float* freqs = (const float*)d_in[1];
  const float* fbias = (const float*)d_in[2];
  const float* gamma = (const float*)d_in[3];
  const float* beta  = (const float*)d_in[4];
  const float* w_qk  = (const float*)d_in[5];
  const float* w_v   = (const float*)d_in[6];
  const float* w_out = (const float*)d_in[7];
  const float* b_out = (const float*)d_in[8];
  float* out = (float*)d_out;

  const size_t T = (size_t)Bb * Nn;  // 8192 tokens
  f16* WqkvT = (f16*)d_ws;                        // [3072][1024]
  f16* WoutT = WqkvT + (size_t)EQKV * DIM;        // [1024][1024]
  f16* Xn    = WoutT + (size_t)DIM * DIM;         // [8192][1024]
  f16* AttO  = Xn + T * DIM;                      // [8192][1024]
  f16* Qp    = AttO + T * DIM;                    // [128][1024][128]
  f16* Kp    = Qp + (size_t)128 * Nn * 128;       // [128][1024][128]
  f16* Vt    = Kp + (size_t)128 * Nn * 128;       // [128][64][1024]

  transpose_cvt<<<dim3(2048 / 32, 1024 / 32), 256, 0, stream>>>(w_qk, WqkvT, DIM, 2048);
  transpose_cvt<<<dim3(1024 / 32, 1024 / 32), 256, 0, stream>>>(w_v, WqkvT + (size_t)2048 * DIM, DIM, 1024);
  transpose_cvt<<<dim3(1024 / 32, 1024 / 32), 256, 0, stream>>>(w_out, WoutT, DIM, DIM);

  ln_kernel<<<(int)T, 256, 0, stream>>>(x, gamma, beta, Xn);

  gemm_qkv_polar<<<(int)(T / 128) * (EQKV / 128), 256, 0, stream>>>(
      Xn, WqkvT, freqs, fbias, Qp, Kp, Vt);

  attn_kernel<<<Bb * Hh * (Nn / 256), 512, 0, stream>>>(Qp, Kp, Vt, AttO);

  gemm_bt<true><<<(int)(T / 128) * (DIM / 128), 256, 0, stream>>>(
      AttO, WoutT, (void*)out, b_out, (int)T, DIM, DIM);
}

// Round 5
// 326.662 us; speedup vs baseline: 1.3547x; 1.3547x over previous
//
#include <hip/hip_runtime.h>
#include <cmath>

using f16   = _Float16;
using f16x2 = __attribute__((ext_vector_type(2))) _Float16;
using f16x4 = __attribute__((ext_vector_type(4))) _Float16;
using f16x8 = __attribute__((ext_vector_type(8))) _Float16;
using f32x4 = __attribute__((ext_vector_type(4))) float;

#define DEV __device__ __forceinline__

// ---- constants ----
constexpr int Bb  = 8;
constexpr int Nn  = 1024;
constexpr int DIM = 1024;
constexpr int Hh  = 16;
constexpr int DH  = 64;
constexpr int EQKV = 3072;   // q(1024) | k(1024) | v(1024)

DEV void async16(const f16* g, f16* l) {
  __builtin_amdgcn_global_load_lds(
      (const __attribute__((address_space(1))) void*)g,
      (__attribute__((address_space(3))) void*)l, 16, 0, 0);
}

DEV float softplusf(float x) {
  // stable softplus; __logf precision (~2^-21 rel) is ample for f16 output
  return fmaxf(x, 0.f) + __logf(1.f + __expf(-fabsf(x)));
}

// DPP rotate-reduce over 16-lane rows.
template <int CTRL>
DEV float dpp_mov(float x) {
  return __builtin_bit_cast(float,
      __builtin_amdgcn_update_dpp(__builtin_bit_cast(int, x), __builtin_bit_cast(int, x),
                                  CTRL, 0xf, 0xf, false));
}
DEV float rmax16(float x) {
  x = fmaxf(x, dpp_mov<0x121>(x));
  x = fmaxf(x, dpp_mov<0x122>(x));
  x = fmaxf(x, dpp_mov<0x124>(x));
  x = fmaxf(x, dpp_mov<0x128>(x));
  return x;
}
DEV float rsum16(float x) {
  x += dpp_mov<0x121>(x);
  x += dpp_mov<0x122>(x);
  x += dpp_mov<0x124>(x);
  x += dpp_mov<0x128>(x);
  return x;
}

// ---------------- transpose + fp32->fp16 convert: dst[c][r] = src[r][c] ----------------
__global__ __launch_bounds__(256) void transpose_cvt(const float* __restrict__ src,
                                                     f16* __restrict__ dst,
                                                     int rows, int cols) {
  __shared__ float tile[32][33];
  int t = threadIdx.x, tx = t & 31, ty = t >> 5;
  int c0 = blockIdx.x * 32, r0 = blockIdx.y * 32;
#pragma unroll
  for (int j = 0; j < 32; j += 8)
    tile[ty + j][tx] = src[(size_t)(r0 + ty + j) * cols + c0 + tx];
  __syncthreads();
#pragma unroll
  for (int j = 0; j < 32; j += 8)
    dst[(size_t)(c0 + ty + j) * rows + r0 + tx] = (f16)tile[tx][ty + j];
}

// ---------------- LayerNorm (fp32 in, fp16 out) ----------------
__global__ __launch_bounds__(256) void ln_kernel(const float* __restrict__ x,
                                                 const float* __restrict__ gamma,
                                                 const float* __restrict__ beta,
                                                 f16* __restrict__ xn) {
  int row = blockIdx.x;
  int t = threadIdx.x;
  const float4* xr = (const float4*)(x + (size_t)row * DIM);
  float4 v = xr[t];
  float s  = v.x + v.y + v.z + v.w;
  float s2 = v.x * v.x + v.y * v.y + v.z * v.z + v.w * v.w;
#pragma unroll
  for (int off = 32; off; off >>= 1) {
    s  += __shfl_xor(s,  off, 64);
    s2 += __shfl_xor(s2, off, 64);
  }
  __shared__ float red[8];
  int wv = t >> 6, lane = t & 63;
  if (lane == 0) { red[wv] = s; red[4 + wv] = s2; }
  __syncthreads();
  s  = red[0] + red[1] + red[2] + red[3];
  s2 = red[4] + red[5] + red[6] + red[7];
  float mu  = s * (1.f / DIM);
  float var = s2 * (1.f / DIM) - mu * mu;
  float rs  = rsqrtf(var + 1e-5f);
  float4 g = ((const float4*)gamma)[t];
  float4 bb = ((const float4*)beta)[t];
  f16x4 o;
  o[0] = (f16)((v.x - mu) * rs * g.x + bb.x);
  o[1] = (f16)((v.y - mu) * rs * g.y + bb.y);
  o[2] = (f16)((v.z - mu) * rs * g.z + bb.z);
  o[3] = (f16)((v.w - mu) * rs * g.w + bb.w);
  ((f16x4*)(xn + (size_t)row * DIM))[t] = o;
}

// ---------------- m97-style GEMM: C[M,E] = A[M,K] * Bt[E,K]^T ----------------
template <bool FP32OUT>
__global__ __launch_bounds__(256) void gemm_bt(const f16* __restrict__ A,
                                               const f16* __restrict__ Bt,
                                               void* __restrict__ Cv,
                                               const float* __restrict__ bias,
                                               int M, int K, int E) {
  __shared__ f16 lA[128 * 32];
  __shared__ f16 lB[128 * 32];
  int tid  = threadIdx.x;
  int lane = tid & 63;
  int wv   = __builtin_amdgcn_readfirstlane(tid >> 6);
  int nbe  = E >> 7;
  int bm = blockIdx.x / nbe, be = blockIdx.x % nbe;
  size_t m0 = (size_t)bm * 128, e0 = (size_t)be * 128;
  int wm = (wv & 1) * 64, we = (wv >> 1) * 64;
  int lm = lane & 15, q = lane >> 4;

  f32x4 acc[4][4] = {};

  int row_s[2], cg_s[2];
#pragma unroll
  for (int r = 0; r < 2; ++r) {
    int s = r * 256 + tid;
    row_s[r] = s >> 2;
    cg_s[r]  = (s & 3) ^ ((row_s[r] >> 1) & 3);
  }
  const f16* pa[4];
  const f16* pb[4];
#pragma unroll
  for (int i = 0; i < 4; ++i) {
    int ra = wm + i * 16 + lm;
    pa[i] = lA + ra * 32 + (q ^ ((ra >> 1) & 3)) * 8;
    int rb = we + i * 16 + lm;
    pb[i] = lB + rb * 32 + (q ^ ((rb >> 1) & 3)) * 8;
  }

  for (int k0 = 0; k0 < K; k0 += 32) {
#pragma unroll
    for (int r = 0; r < 2; ++r) {
      const f16* ga = A  + (m0 + row_s[r]) * K + k0 + cg_s[r] * 8;
      const f16* gb = Bt + (e0 + row_s[r]) * K + k0 + cg_s[r] * 8;
      async16(ga, lA + (r * 256 + wv * 64) * 8);
      async16(gb, lB + (r * 256 + wv * 64) * 8);
    }
    __syncthreads();
    f16x8 af[4], bf[4];
#pragma unroll
    for (int i = 0; i < 4; ++i) {
      af[i] = *(const f16x8*)pa[i];
      bf[i] = *(const f16x8*)pb[i];
    }
#pragma unroll
    for (int i = 0; i < 4; ++i)
#pragma unroll
      for (int j = 0; j < 4; ++j)
        acc[i][j] = __builtin_amdgcn_mfma_f32_16x16x32_f16(af[i], bf[j], acc[i][j], 0, 0, 0);
    __syncthreads();
  }

#pragma unroll
  for (int i = 0; i < 4; ++i) {
    size_t mbase = m0 + wm + i * 16 + q * 4;
#pragma unroll
    for (int j = 0; j < 4; ++j) {
      size_t e = e0 + we + j * 16 + lm;
#pragma unroll
      for (int g = 0; g < 4; ++g) {
        float val = acc[i][j][g];
        if (FP32OUT)
          ((float*)Cv)[(mbase + g) * (size_t)E + e] = val + bias[e];
        else
          ((f16*)Cv)[(mbase + g) * (size_t)E + e] = (f16)val;
      }
    }
  }
}

// ---------------- polar precompute v2 (pair-of-d, vectorized I/O) ----------------
__global__ __launch_bounds__(256) void polar_kernel(const f16* __restrict__ qkv,
                                                    const float* __restrict__ freqs,
                                                    const float* __restrict__ fbias,
                                                    f16* __restrict__ Qp,
                                                    f16* __restrict__ Kp,
                                                    f16* __restrict__ Vt) {
  __shared__ f16 vt[64 * 66];
  int tid = threadIdx.x;
  int bx = blockIdx.x;
  int nt = bx & 15, bh = bx >> 4;
  int b = bh >> 4, h = bh & 15;
  size_t tok0 = (size_t)b * Nn + nt * 64;
  int n0 = nt * 64;
  constexpr float kScale = 0.125f;  // DH^-0.5 folded into Q
#pragma unroll
  for (int i = 0; i < 8; ++i) {
    int e2 = tid + i * 256;             // 0..2047 (nl, d-pair)
    int nl = e2 >> 5, dp = (e2 & 31) * 2;
    size_t src = (tok0 + nl) * EQKV + h * 64 + dp;
    f16x2 q2 = *(const f16x2*)(qkv + src);
    f16x2 k2 = *(const f16x2*)(qkv + src + 1024);
    f16x2 v2 = *(const f16x2*)(qkv + src + 2048);
    int fidx = (n0 + nl) * 64 + dp;
    float2 f2  = *(const float2*)(freqs + fidx);
    float2 fb2 = *(const float2*)(fbias + fidx);
    f16x2 qc, qs, kc, ksn;
#pragma unroll
    for (int u = 0; u < 2; ++u) {
      float fq = u ? f2.y : f2.x;
      float fk = fq + (u ? fb2.y : fb2.x);
      float spq = softplusf((float)q2[u]) * kScale;
      float spk = softplusf((float)k2[u]);
      float snq, csq, snk, csk;
      __sincosf(fq, &snq, &csq);
      __sincosf(fk, &snk, &csk);
      qc[u]  = (f16)(spq * csq);
      qs[u]  = (f16)(spq * snq);
      kc[u]  = (f16)(spk * csk);
      ksn[u] = (f16)(spk * snk);
    }
    size_t dst = ((size_t)bh * Nn + n0 + nl) * 128 + dp;
    *(f16x2*)(Qp + dst)      = qc;
    *(f16x2*)(Qp + dst + 64) = qs;
    *(f16x2*)(Kp + dst)      = kc;
    *(f16x2*)(Kp + dst + 64) = ksn;
    vt[dp * 66 + nl]       = v2[0];
    vt[(dp + 1) * 66 + nl] = v2[1];
  }
  __syncthreads();
#pragma unroll
  for (int i = 0; i < 16; ++i) {
    int e = tid + i * 256;
    int d = e >> 6, nl = e & 63;
    Vt[((size_t)bh * 64 + d) * Nn + n0 + nl] = vt[d * 66 + nl];
  }
}

// ---------------- flash attention v3: 512 thr / 8 waves x 16 q-rows ----------------
// Per-wave state ~95 VGPRs -> fits the 128-reg / 4-waves-per-SIMD point without spills.
// LDS 56 KB -> 2 blocks/CU = 16 waves/CU.  One barrier per kt; K/V double-buffered DMA.
constexpr int AK0 = 0;
constexpr int AK1 = 8192;
constexpr int AV0 = 16384;
constexpr int AV1 = 20480;
constexpr int APB = 24576;

__global__ __launch_bounds__(512, 4) void attn_kernel(const f16* __restrict__ Qp,
                                                      const f16* __restrict__ Kp,
                                                      const f16* __restrict__ Vt,
                                                      f16* __restrict__ attout) {
  __shared__ f16 smem[28672];  // 56 KB

  int tid = threadIdx.x, lane = tid & 63;
  int wv = __builtin_amdgcn_readfirstlane(tid >> 6);  // 0..7
  int lm = lane & 15, q = lane >> 4;
  int bx = blockIdx.x;
  int bh = (bx & 7) | ((bx >> 6) << 3);  // XCD swizzle: same head -> same bx%8
  int qt = (bx >> 3) & 7;                // 8 q-tiles of 128 rows
  const f16* Kbase = Kp + (size_t)bh * Nn * 128;
  const f16* Vbase = Vt + (size_t)bh * 64 * Nn;

  // ---- prologue: DMA K/V tile 0 ----
#pragma unroll
  for (int i = 0; i < 2; ++i) {
    int s = i * 512 + tid;
    int r = s >> 4, c = s & 15;
    int g = c ^ (r & 15);
    async16(Kbase + (size_t)r * 128 + g * 8, smem + AK0 + (i * 512 + wv * 64) * 8);
  }
  {
    int r = tid >> 3, c = tid & 7;
    int g = c ^ (r & 7);
    async16(Vbase + (size_t)r * Nn + g * 8, smem + AV0 + (wv * 64) * 8);
  }

  // ---- Q frags (16 rows/wave) straight from global ----
  f16x8 qf[4];
  {
    const f16* Qb = Qp + ((size_t)bh * Nn + qt * 128 + wv * 16 + lm) * 128;
#pragma unroll
    for (int ks = 0; ks < 4; ++ks)
      qf[ks] = *(const f16x8*)(Qb + ks * 32 + q * 8);
  }

  f32x4 O[4] = {};
  float mrow[4], lrow[4];
#pragma unroll
  for (int g = 0; g < 4; ++g) { mrow[g] = -INFINITY; lrow[g] = 0.f; }
  f16* sP = smem + APB + wv * 512;  // wave-private 16x32

  for (int kt = 0; kt < 16; ++kt) {
    __syncthreads();  // tile kt ready (its DMA was issued a full compute-phase ago)

    if (kt < 15) {
      f16* nK = smem + ((kt & 1) ? AK0 : AK1);
      f16* nV = smem + ((kt & 1) ? AV0 : AV1);
#pragma unroll
      for (int i = 0; i < 2; ++i) {
        int s = i * 512 + tid;
        int r = s >> 4, c = s & 15;
        int g = c ^ (r & 15);
        async16(Kbase + (size_t)((kt + 1) * 64 + r) * 128 + g * 8, nK + (i * 512 + wv * 64) * 8);
      }
      {
        int r = tid >> 3, c = tid & 7;
        int g = c ^ (r & 7);
        async16(Vbase + (size_t)r * Nn + (kt + 1) * 64 + g * 8, nV + (wv * 64) * 8);
      }
    }
    const f16* sK = smem + ((kt & 1) ? AK1 : AK0);
    const f16* sV = smem + ((kt & 1) ? AV1 : AV0);

    // ---- S = Qp * Kp^T (16 q-rows x 64 keys) ----
    f32x4 S[4] = {};
#pragma unroll
    for (int nt = 0; nt < 4; ++nt) {
      f16x8 kf[4];
#pragma unroll
      for (int ks = 0; ks < 4; ++ks)
        kf[ks] = *(const f16x8*)(sK + (nt * 16 + lm) * 128 + (((ks * 4 + q) ^ lm) * 8));
#pragma unroll
      for (int ks = 0; ks < 4; ++ks)
        S[nt] = __builtin_amdgcn_mfma_f32_16x16x32_f16(qf[ks], kf[ks], S[nt], 0, 0, 0);
    }

    // ---- online softmax (DPP rotate-reduce) ----
#pragma unroll
    for (int g = 0; g < 4; ++g) {
      float mx = fmaxf(fmaxf(S[0][g], S[1][g]), fmaxf(S[2][g], S[3][g]));
      mx = rmax16(mx);
      float mn = fmaxf(mrow[g], mx);
      float alpha = __expf(mrow[g] - mn);
      mrow[g] = mn;
      float rs = 0.f;
#pragma unroll
      for (int nt = 0; nt < 4; ++nt) {
        float p = __expf(S[nt][g] - mn);
        S[nt][g] = p;
        rs += p;
      }
      rs = rsum16(rs);
      lrow[g] = lrow[g] * alpha + rs;
#pragma unroll
      for (int nt = 0; nt < 4; ++nt) O[nt][g] *= alpha;
    }

    // ---- PV in two 32-key halves via wave-private P ----
#pragma unroll
    for (int half = 0; half < 2; ++half) {
      __asm__ __volatile__("" ::: "memory");
#pragma unroll
      for (int ntl = 0; ntl < 2; ++ntl) {
        int nt = half * 2 + ntl;
#pragma unroll
        for (int g = 0; g < 4; ++g) {
          int rl = q * 4 + g;
          int ch = (ntl * 2 + (lm >> 3)) ^ q;  // (rl>>2)&3 == q
          sP[rl * 32 + ch * 8 + (lm & 7)] = (f16)S[nt][g];
        }
      }
      __asm__ __volatile__("" ::: "memory");
      f16x8 pf = *(const f16x8*)(sP + lm * 32 + ((q ^ ((lm >> 2) & 3)) * 8));
#pragma unroll
      for (int nto = 0; nto < 4; ++nto) {
        int row = nto * 16 + lm;
        f16x8 vf = *(const f16x8*)(sV + row * 64 + (((half * 4 + q) ^ (row & 7)) * 8));
        O[nto] = __builtin_amdgcn_mfma_f32_16x16x32_f16(pf, vf, O[nto], 0, 0, 0);
      }
    }
  }

  // ---- epilogue ----
  int b = bh >> 4, h = bh & 15;
  size_t tok0 = (size_t)b * Nn + qt * 128 + wv * 16;
#pragma unroll
  for (int g = 0; g < 4; ++g) {
    size_t token = tok0 + q * 4 + g;
    float inv = 1.f / lrow[g];
#pragma unroll
    for (int nto = 0; nto < 4; ++nto)
      attout[token * (size_t)(Hh * DH) + h * 64 + nto * 16 + lm] =
          (f16)(O[nto][g] * inv);
  }
}

// ---------------- launch ----------------
extern "C" void kernel_launch(void* const* d_in, const int* in_sizes, int n_in,
                              void* d_out, int out_size, void* d_ws, size_t ws_size,
                              hipStream_t stream) {
  const float* x     = (const float*)d_in[0];
  const float* freqs = (const float*)d_in[1];
  const float* fbias = (const float*)d_in[2];
  const float* gamma = (const float*)d_in[3];
  const float* beta  = (const float*)d_in[4];
  const float* w_qk  = (const float*)d_in[5];
  const float* w_v   = (const float*)d_in[6];
  const float* w_out = (const float*)d_in[7];
  const float* b_out = (const float*)d_in[8];
  float* out = (float*)d_out;

  const size_t T = (size_t)Bb * Nn;  // 8192 tokens
  f16* WqkvT = (f16*)d_ws;                        // [3072][1024]
  f16* WoutT = WqkvT + (size_t)EQKV * DIM;        // [1024][1024]
  f16* Xn    = WoutT + (size_t)DIM * DIM;         // [8192][1024]
  f16* QKV   = Xn + T * DIM;                      // [8192][3072]
  f16* AttO  = QKV + T * EQKV;                    // [8192][1024]
  f16* Qp    = AttO + T * DIM;                    // [128][1024][128]
  f16* Kp    = Qp + (size_t)128 * Nn * 128;       // [128][1024][128]
  f16* Vt    = Kp + (size_t)128 * Nn * 128;       // [128][64][1024]

  transpose_cvt<<<dim3(2048 / 32, 1024 / 32), 256, 0, stream>>>(w_qk, WqkvT, DIM, 2048);
  transpose_cvt<<<dim3(1024 / 32, 1024 / 32), 256, 0, stream>>>(w_v, WqkvT + (size_t)2048 * DIM, DIM, 1024);
  transpose_cvt<<<dim3(1024 / 32, 1024 / 32), 256, 0, stream>>>(w_out, WoutT, DIM, DIM);

  ln_kernel<<<(int)T, 256, 0, stream>>>(x, gamma, beta, Xn);

  gemm_bt<false><<<(int)(T / 128) * (EQKV / 128), 256, 0, stream>>>(
      Xn, WqkvT, (void*)QKV, nullptr, (int)T, DIM, EQKV);

  polar_kernel<<<Bb * Hh * (Nn / 64), 256, 0, stream>>>(QKV, freqs, fbias, Qp, Kp, Vt);

  attn_kernel<<<Bb * Hh * (Nn / 128), 512, 0, stream>>>(Qp, Kp, Vt, AttO);

  gemm_bt<true><<<(int)(T / 128) * (DIM / 128), 256, 0, stream>>>(
      AttO, WoutT, (void*)out, b_out, (int)T, DIM, DIM);
}

// Round 6
// 315.898 us; speedup vs baseline: 1.4008x; 1.0341x over previous
//
#include <hip/hip_runtime.h>
#include <cmath>

using f16   = _Float16;
using f16x2 = __attribute__((ext_vector_type(2))) _Float16;
using f16x4 = __attribute__((ext_vector_type(4))) _Float16;
using f16x8 = __attribute__((ext_vector_type(8))) _Float16;
using f32x4 = __attribute__((ext_vector_type(4))) float;

#define DEV __device__ __forceinline__

// ---- constants ----
constexpr int Bb  = 8;
constexpr int Nn  = 1024;
constexpr int DIM = 1024;
constexpr int Hh  = 16;
constexpr int DH  = 64;
constexpr int EQKV = 3072;   // q(1024) | k(1024) | v(1024)

DEV void async16(const f16* g, f16* l) {
  __builtin_amdgcn_global_load_lds(
      (const __attribute__((address_space(1))) void*)g,
      (__attribute__((address_space(3))) void*)l, 16, 0, 0);
}

DEV float softplusf(float x) {
  // stable softplus; __logf precision (~2^-21 rel) is ample for f16 output
  return fmaxf(x, 0.f) + __logf(1.f + __expf(-fabsf(x)));
}

// ---------------- transpose + fp32->fp16 convert: dst[c][r] = src[r][c] ----------------
__global__ __launch_bounds__(256) void transpose_cvt(const float* __restrict__ src,
                                                     f16* __restrict__ dst,
                                                     int rows, int cols) {
  __shared__ float tile[32][33];
  int t = threadIdx.x, tx = t & 31, ty = t >> 5;
  int c0 = blockIdx.x * 32, r0 = blockIdx.y * 32;
#pragma unroll
  for (int j = 0; j < 32; j += 8)
    tile[ty + j][tx] = src[(size_t)(r0 + ty + j) * cols + c0 + tx];
  __syncthreads();
#pragma unroll
  for (int j = 0; j < 32; j += 8)
    dst[(size_t)(c0 + ty + j) * rows + r0 + tx] = (f16)tile[tx][ty + j];
}

// ---------------- LayerNorm (fp32 in, fp16 out) ----------------
__global__ __launch_bounds__(256) void ln_kernel(const float* __restrict__ x,
                                                 const float* __restrict__ gamma,
                                                 const float* __restrict__ beta,
                                                 f16* __restrict__ xn) {
  int row = blockIdx.x;
  int t = threadIdx.x;
  const float4* xr = (const float4*)(x + (size_t)row * DIM);
  float4 v = xr[t];
  float s  = v.x + v.y + v.z + v.w;
  float s2 = v.x * v.x + v.y * v.y + v.z * v.z + v.w * v.w;
#pragma unroll
  for (int off = 32; off; off >>= 1) {
    s  += __shfl_xor(s,  off, 64);
    s2 += __shfl_xor(s2, off, 64);
  }
  __shared__ float red[8];
  int wv = t >> 6, lane = t & 63;
  if (lane == 0) { red[wv] = s; red[4 + wv] = s2; }
  __syncthreads();
  s  = red[0] + red[1] + red[2] + red[3];
  s2 = red[4] + red[5] + red[6] + red[7];
  float mu  = s * (1.f / DIM);
  float var = s2 * (1.f / DIM) - mu * mu;
  float rs  = rsqrtf(var + 1e-5f);
  float4 g = ((const float4*)gamma)[t];
  float4 bb = ((const float4*)beta)[t];
  f16x4 o;
  o[0] = (f16)((v.x - mu) * rs * g.x + bb.x);
  o[1] = (f16)((v.y - mu) * rs * g.y + bb.y);
  o[2] = (f16)((v.z - mu) * rs * g.z + bb.z);
  o[3] = (f16)((v.w - mu) * rs * g.w + bb.w);
  ((f16x4*)(xn + (size_t)row * DIM))[t] = o;
}

// ---------------- m97-style GEMM: C[M,E] = A[M,K] * Bt[E,K]^T ----------------
template <bool FP32OUT>
__global__ __launch_bounds__(256) void gemm_bt(const f16* __restrict__ A,
                                               const f16* __restrict__ Bt,
                                               void* __restrict__ Cv,
                                               const float* __restrict__ bias,
                                               int M, int K, int E) {
  __shared__ f16 lA[128 * 32];
  __shared__ f16 lB[128 * 32];
  int tid  = threadIdx.x;
  int lane = tid & 63;
  int wv   = __builtin_amdgcn_readfirstlane(tid >> 6);
  int nbe  = E >> 7;
  int bm = blockIdx.x / nbe, be = blockIdx.x % nbe;
  size_t m0 = (size_t)bm * 128, e0 = (size_t)be * 128;
  int wm = (wv & 1) * 64, we = (wv >> 1) * 64;
  int lm = lane & 15, q = lane >> 4;

  f32x4 acc[4][4] = {};

  int row_s[2], cg_s[2];
#pragma unroll
  for (int r = 0; r < 2; ++r) {
    int s = r * 256 + tid;
    row_s[r] = s >> 2;
    cg_s[r]  = (s & 3) ^ ((row_s[r] >> 1) & 3);
  }
  const f16* pa[4];
  const f16* pb[4];
#pragma unroll
  for (int i = 0; i < 4; ++i) {
    int ra = wm + i * 16 + lm;
    pa[i] = lA + ra * 32 + (q ^ ((ra >> 1) & 3)) * 8;
    int rb = we + i * 16 + lm;
    pb[i] = lB + rb * 32 + (q ^ ((rb >> 1) & 3)) * 8;
  }

  for (int k0 = 0; k0 < K; k0 += 32) {
#pragma unroll
    for (int r = 0; r < 2; ++r) {
      const f16* ga = A  + (m0 + row_s[r]) * K + k0 + cg_s[r] * 8;
      const f16* gb = Bt + (e0 + row_s[r]) * K + k0 + cg_s[r] * 8;
      async16(ga, lA + (r * 256 + wv * 64) * 8);
      async16(gb, lB + (r * 256 + wv * 64) * 8);
    }
    __syncthreads();
    f16x8 af[4], bf[4];
#pragma unroll
    for (int i = 0; i < 4; ++i) {
      af[i] = *(const f16x8*)pa[i];
      bf[i] = *(const f16x8*)pb[i];
    }
#pragma unroll
    for (int i = 0; i < 4; ++i)
#pragma unroll
      for (int j = 0; j < 4; ++j)
        acc[i][j] = __builtin_amdgcn_mfma_f32_16x16x32_f16(af[i], bf[j], acc[i][j], 0, 0, 0);
    __syncthreads();
  }

#pragma unroll
  for (int i = 0; i < 4; ++i) {
    size_t mbase = m0 + wm + i * 16 + q * 4;
#pragma unroll
    for (int j = 0; j < 4; ++j) {
      size_t e = e0 + we + j * 16 + lm;
#pragma unroll
      for (int g = 0; g < 4; ++g) {
        float val = acc[i][j][g];
        if (FP32OUT)
          ((float*)Cv)[(mbase + g) * (size_t)E + e] = val + bias[e];
        else
          ((f16*)Cv)[(mbase + g) * (size_t)E + e] = (f16)val;
      }
    }
  }
}

// ---------------- polar precompute (pair-of-d, vectorized I/O) ----------------
__global__ __launch_bounds__(256) void polar_kernel(const f16* __restrict__ qkv,
                                                    const float* __restrict__ freqs,
                                                    const float* __restrict__ fbias,
                                                    f16* __restrict__ Qp,
                                                    f16* __restrict__ Kp,
                                                    f16* __restrict__ Vt) {
  __shared__ f16 vt[64 * 66];
  int tid = threadIdx.x;
  int bx = blockIdx.x;
  int nt = bx & 15, bh = bx >> 4;
  int b = bh >> 4, h = bh & 15;
  size_t tok0 = (size_t)b * Nn + nt * 64;
  int n0 = nt * 64;
  constexpr float kScale = 0.125f;  // DH^-0.5 folded into Q
#pragma unroll
  for (int i = 0; i < 8; ++i) {
    int e2 = tid + i * 256;             // 0..2047 (nl, d-pair)
    int nl = e2 >> 5, dp = (e2 & 31) * 2;
    size_t src = (tok0 + nl) * EQKV + h * 64 + dp;
    f16x2 q2 = *(const f16x2*)(qkv + src);
    f16x2 k2 = *(const f16x2*)(qkv + src + 1024);
    f16x2 v2 = *(const f16x2*)(qkv + src + 2048);
    int fidx = (n0 + nl) * 64 + dp;
    float2 f2  = *(const float2*)(freqs + fidx);
    float2 fb2 = *(const float2*)(fbias + fidx);
    f16x2 qc, qs, kc, ksn;
#pragma unroll
    for (int u = 0; u < 2; ++u) {
      float fq = u ? f2.y : f2.x;
      float fk = fq + (u ? fb2.y : fb2.x);
      float spq = softplusf((float)q2[u]) * kScale;
      float spk = softplusf((float)k2[u]);
      float snq, csq, snk, csk;
      __sincosf(fq, &snq, &csq);
      __sincosf(fk, &snk, &csk);
      qc[u]  = (f16)(spq * csq);
      qs[u]  = (f16)(spq * snq);
      kc[u]  = (f16)(spk * csk);
      ksn[u] = (f16)(spk * snk);
    }
    size_t dst = ((size_t)bh * Nn + n0 + nl) * 128 + dp;
    *(f16x2*)(Qp + dst)      = qc;
    *(f16x2*)(Qp + dst + 64) = qs;
    *(f16x2*)(Kp + dst)      = kc;
    *(f16x2*)(Kp + dst + 64) = ksn;
    vt[dp * 66 + nl]       = v2[0];
    vt[(dp + 1) * 66 + nl] = v2[1];
  }
  __syncthreads();
#pragma unroll
  for (int i = 0; i < 16; ++i) {
    int e = tid + i * 256;
    int d = e >> 6, nl = e & 63;
    Vt[((size_t)bh * 64 + d) * Nn + n0 + nl] = vt[d * 66 + nl];
  }
}

// ---------------- flash attention v4: S^T trick, no P LDS round-trip ----------------
// S^T = Kp·Qp^T via 16x16x32 (M=key, N=qrow).  Its C-layout (col=qrow, row=key q*4+g)
// IS the B-operand layout of 16x16x16 MFMA -> post-softmax P feeds PV straight from
// registers.  O^T += V^T·P^T; V^T is the A operand (f16x4 from swizzled sV).
// Per-lane softmax state is scalar (every lane's 16 S values share one q-row).
// LDS 48 KB (K dbuf 32 + V dbuf 16, no P) -> 3 blocks/CU = 24 waves/CU.
constexpr int AK0 = 0;
constexpr int AK1 = 8192;
constexpr int AV0 = 16384;
constexpr int AV1 = 20480;

__global__ __launch_bounds__(512, 6) void attn_kernel(const f16* __restrict__ Qp,
                                                      const f16* __restrict__ Kp,
                                                      const f16* __restrict__ Vt,
                                                      f16* __restrict__ attout) {
  __shared__ f16 smem[24576];  // 48 KB

  int tid = threadIdx.x, lane = tid & 63;
  int wv = __builtin_amdgcn_readfirstlane(tid >> 6);  // 0..7
  int lm = lane & 15, q = lane >> 4;
  int bx = blockIdx.x;
  int bh = (bx & 7) | ((bx >> 6) << 3);  // XCD swizzle: same head -> same bx%8
  int qt = (bx >> 3) & 7;                // 8 q-tiles of 128 rows
  const f16* Kbase = Kp + (size_t)bh * Nn * 128;
  const f16* Vbase = Vt + (size_t)bh * 64 * Nn;

  // ---- prologue: DMA K/V tile 0 ----
#pragma unroll
  for (int i = 0; i < 2; ++i) {
    int s = i * 512 + tid;
    int r = s >> 4, c = s & 15;
    int g = c ^ (r & 15);
    async16(Kbase + (size_t)r * 128 + g * 8, smem + AK0 + (i * 512 + wv * 64) * 8);
  }
  {
    int r = tid >> 3, c = tid & 7;
    int g = c ^ (r & 7);
    async16(Vbase + (size_t)r * Nn + g * 8, smem + AV0 + (wv * 64) * 8);
  }

  // ---- Q frags (16 rows/wave), used as the B operand of S^T ----
  f16x8 qf[4];
  {
    const f16* Qb = Qp + ((size_t)bh * Nn + qt * 128 + wv * 16 + lm) * 128;
#pragma unroll
    for (int ks = 0; ks < 4; ++ks)
      qf[ks] = *(const f16x8*)(Qb + ks * 32 + q * 8);
  }

  f32x4 O[4] = {};           // O^T: row = d (q*4+g within tile nto), col = qrow (lm)
  float mrow = -INFINITY, lrow = 0.f;  // scalar per lane (qrow = lm)

  for (int kt = 0; kt < 16; ++kt) {
    __syncthreads();  // tile kt ready (its DMA was issued a full compute-phase ago)

    if (kt < 15) {
      f16* nK = smem + ((kt & 1) ? AK0 : AK1);
      f16* nV = smem + ((kt & 1) ? AV0 : AV1);
#pragma unroll
      for (int i = 0; i < 2; ++i) {
        int s = i * 512 + tid;
        int r = s >> 4, c = s & 15;
        int g = c ^ (r & 15);
        async16(Kbase + (size_t)((kt + 1) * 64 + r) * 128 + g * 8, nK + (i * 512 + wv * 64) * 8);
      }
      {
        int r = tid >> 3, c = tid & 7;
        int g = c ^ (r & 7);
        async16(Vbase + (size_t)r * Nn + (kt + 1) * 64 + g * 8, nV + (wv * 64) * 8);
      }
    }
    const f16* sK = smem + ((kt & 1) ? AK1 : AK0);
    const f16* sV = smem + ((kt & 1) ? AV1 : AV0);

    // ---- S^T = Kp * Qp^T (64 keys x 16 q-rows) ----
    f32x4 S[4] = {};
#pragma unroll
    for (int nt = 0; nt < 4; ++nt) {
      f16x8 kf[4];
#pragma unroll
      for (int ks = 0; ks < 4; ++ks)
        kf[ks] = *(const f16x8*)(sK + (nt * 16 + lm) * 128 + (((ks * 4 + q) ^ lm) * 8));
#pragma unroll
      for (int ks = 0; ks < 4; ++ks)
        S[nt] = __builtin_amdgcn_mfma_f32_16x16x32_f16(kf[ks], qf[ks], S[nt], 0, 0, 0);
    }

    // ---- online softmax: all 16 S values in this lane share q-row lm ----
    float mx = -INFINITY;
#pragma unroll
    for (int nt = 0; nt < 4; ++nt)
#pragma unroll
      for (int g = 0; g < 4; ++g) mx = fmaxf(mx, S[nt][g]);
    mx = fmaxf(mx, __shfl_xor(mx, 16, 64));
    mx = fmaxf(mx, __shfl_xor(mx, 32, 64));
    float mn = fmaxf(mrow, mx);
    float alpha = __expf(mrow - mn);
    mrow = mn;
    float rs = 0.f;
    f16x4 pf[4];
#pragma unroll
    for (int nt = 0; nt < 4; ++nt) {
#pragma unroll
      for (int g = 0; g < 4; ++g) {
        float p = __expf(S[nt][g] - mn);
        S[nt][g] = p;
        rs += p;
      }
      pf[nt][0] = (f16)S[nt][0];
      pf[nt][1] = (f16)S[nt][1];
      pf[nt][2] = (f16)S[nt][2];
      pf[nt][3] = (f16)S[nt][3];
    }
    rs += __shfl_xor(rs, 16, 64);
    rs += __shfl_xor(rs, 32, 64);
    lrow = lrow * alpha + rs;
#pragma unroll
    for (int nto = 0; nto < 4; ++nto)
#pragma unroll
      for (int g = 0; g < 4; ++g) O[nto][g] *= alpha;

    // ---- O^T += V^T(tile nto,nt) * P^T(nt), P frag straight from registers ----
#pragma unroll
    for (int nto = 0; nto < 4; ++nto) {
      int r = nto * 16 + lm;
#pragma unroll
      for (int nt = 0; nt < 4; ++nt) {
        int c16 = (nt * 2 + (q >> 1)) ^ (r & 7);
        f16x4 vf = *(const f16x4*)(sV + r * 64 + c16 * 8 + (q & 1) * 4);
        O[nto] = __builtin_amdgcn_mfma_f32_16x16x16f16(vf, pf[nt], O[nto], 0, 0, 0);
      }
    }
  }

  // ---- epilogue: O^T col=qrow -> token = tok0+lm; rows = d, packed f16x4 ----
  int b = bh >> 4, h = bh & 15;
  size_t token = (size_t)b * Nn + qt * 128 + wv * 16 + lm;
  float inv = 1.f / lrow;
#pragma unroll
  for (int nto = 0; nto < 4; ++nto) {
    f16x4 o4;
#pragma unroll
    for (int g = 0; g < 4; ++g) o4[g] = (f16)(O[nto][g] * inv);
    *(f16x4*)(attout + token * (size_t)(Hh * DH) + h * 64 + nto * 16 + q * 4) = o4;
  }
}

// ---------------- launch ----------------
extern "C" void kernel_launch(void* const* d_in, const int* in_sizes, int n_in,
                              void* d_out, int out_size, void* d_ws, size_t ws_size,
                              hipStream_t stream) {
  const float* x     = (const float*)d_in[0];
  const float* freqs = (const float*)d_in[1];
  const float* fbias = (const float*)d_in[2];
  const float* gamma = (const float*)d_in[3];
  const float* beta  = (const float*)d_in[4];
  const float* w_qk  = (const float*)d_in[5];
  const float* w_v   = (const float*)d_in[6];
  const float* w_out = (const float*)d_in[7];
  const float* b_out = (const float*)d_in[8];
  float* out = (float*)d_out;

  const size_t T = (size_t)Bb * Nn;  // 8192 tokens
  f16* WqkvT = (f16*)d_ws;                        // [3072][1024]
  f16* WoutT = WqkvT + (size_t)EQKV * DIM;        // [1024][1024]
  f16* Xn    = WoutT + (size_t)DIM * DIM;         // [8192][1024]
  f16* QKV   = Xn + T * DIM;                      // [8192][3072]
  f16* AttO  = QKV + T * EQKV;                    // [8192][1024]
  f16* Qp    = AttO + T * DIM;                    // [128][1024][128]
  f16* Kp    = Qp + (size_t)128 * Nn * 128;       // [128][1024][128]
  f16* Vt    = Kp + (size_t)128 * Nn * 128;       // [128][64][1024]

  transpose_cvt<<<dim3(2048 / 32, 1024 / 32), 256, 0, stream>>>(w_qk, WqkvT, DIM, 2048);
  transpose_cvt<<<dim3(1024 / 32, 1024 / 32), 256, 0, stream>>>(w_v, WqkvT + (size_t)2048 * DIM, DIM, 1024);
  transpose_cvt<<<dim3(1024 / 32, 1024 / 32), 256, 0, stream>>>(w_out, WoutT, DIM, DIM);

  ln_kernel<<<(int)T, 256, 0, stream>>>(x, gamma, beta, Xn);

  gemm_bt<false><<<(int)(T / 128) * (EQKV / 128), 256, 0, stream>>>(
      Xn, WqkvT, (void*)QKV, nullptr, (int)T, DIM, EQKV);

  polar_kernel<<<Bb * Hh * (Nn / 64), 256, 0, stream>>>(QKV, freqs, fbias, Qp, Kp, Vt);

  attn_kernel<<<Bb * Hh * (Nn / 128), 512, 0, stream>>>(Qp, Kp, Vt, AttO);

  gemm_bt<true><<<(int)(T / 128) * (DIM / 128), 256, 0, stream>>>(
      AttO, WoutT, (void*)out, b_out, (int)T, DIM, DIM);
}

// Round 7
// 311.868 us; speedup vs baseline: 1.4189x; 1.0129x over previous
//
#include <hip/hip_runtime.h>
#include <cmath>

using f16   = _Float16;
using f16x2 = __attribute__((ext_vector_type(2))) _Float16;
using f16x4 = __attribute__((ext_vector_type(4))) _Float16;
using f16x8 = __attribute__((ext_vector_type(8))) _Float16;
using f32x4 = __attribute__((ext_vector_type(4))) float;

#define DEV __device__ __forceinline__

// ---- constants ----
constexpr int Bb  = 8;
constexpr int Nn  = 1024;
constexpr int DIM = 1024;
constexpr int Hh  = 16;
constexpr int DH  = 64;
constexpr int EQKV = 3072;   // q(1024) | k(1024) | v(1024)

DEV void async16(const f16* g, f16* l) {
  __builtin_amdgcn_global_load_lds(
      (const __attribute__((address_space(1))) void*)g,
      (__attribute__((address_space(3))) void*)l, 16, 0, 0);
}

DEV float softplusf(float x) {
  return fmaxf(x, 0.f) + __logf(1.f + __expf(-fabsf(x)));
}

// ---------------- fused 3-way transpose + fp32->fp16 convert ----------------
// z=0: w_qk [1024,2048] -> d0[2048,1024]; z=1: w_v -> d0+2048*1024; z=2: w_out -> d2
__global__ __launch_bounds__(256) void transpose_cvt3(const float* __restrict__ s0,
                                                      const float* __restrict__ s1,
                                                      const float* __restrict__ s2,
                                                      f16* __restrict__ d0,
                                                      f16* __restrict__ d2) {
  __shared__ float tile[32][33];
  const float* src; f16* dst; int cols;
  int bz = blockIdx.z;
  if (bz == 0)      { src = s0; dst = d0;                        cols = 2048; }
  else if (bz == 1) { src = s1; dst = d0 + (size_t)2048 * 1024;  cols = 1024; }
  else              { src = s2; dst = d2;                        cols = 1024; }
  int c0 = blockIdx.x * 32, r0 = blockIdx.y * 32;
  if (c0 >= cols) return;
  int t = threadIdx.x, tx = t & 31, ty = t >> 5;
#pragma unroll
  for (int j = 0; j < 32; j += 8)
    tile[ty + j][tx] = src[(size_t)(r0 + ty + j) * cols + c0 + tx];
  __syncthreads();
#pragma unroll
  for (int j = 0; j < 32; j += 8)
    dst[(size_t)(c0 + ty + j) * 1024 + r0 + tx] = (f16)tile[tx][ty + j];
}

// ---------------- LayerNorm (fp32 in, fp16 out) ----------------
__global__ __launch_bounds__(256) void ln_kernel(const float* __restrict__ x,
                                                 const float* __restrict__ gamma,
                                                 const float* __restrict__ beta,
                                                 f16* __restrict__ xn) {
  int row = blockIdx.x;
  int t = threadIdx.x;
  const float4* xr = (const float4*)(x + (size_t)row * DIM);
  float4 v = xr[t];
  float s  = v.x + v.y + v.z + v.w;
  float s2 = v.x * v.x + v.y * v.y + v.z * v.z + v.w * v.w;
#pragma unroll
  for (int off = 32; off; off >>= 1) {
    s  += __shfl_xor(s,  off, 64);
    s2 += __shfl_xor(s2, off, 64);
  }
  __shared__ float red[8];
  int wv = t >> 6, lane = t & 63;
  if (lane == 0) { red[wv] = s; red[4 + wv] = s2; }
  __syncthreads();
  s  = red[0] + red[1] + red[2] + red[3];
  s2 = red[4] + red[5] + red[6] + red[7];
  float mu  = s * (1.f / DIM);
  float var = s2 * (1.f / DIM) - mu * mu;
  float rs  = rsqrtf(var + 1e-5f);
  float4 g = ((const float4*)gamma)[t];
  float4 bb = ((const float4*)beta)[t];
  f16x4 o;
  o[0] = (f16)((v.x - mu) * rs * g.x + bb.x);
  o[1] = (f16)((v.y - mu) * rs * g.y + bb.y);
  o[2] = (f16)((v.z - mu) * rs * g.z + bb.z);
  o[3] = (f16)((v.w - mu) * rs * g.w + bb.w);
  ((f16x4*)(xn + (size_t)row * DIM))[t] = o;
}

// ---------------- m97-style GEMM: C[M,E] = A[M,K] * Bt[E,K]^T ----------------
template <bool FP32OUT>
__global__ __launch_bounds__(256) void gemm_bt(const f16* __restrict__ A,
                                               const f16* __restrict__ Bt,
                                               void* __restrict__ Cv,
                                               const float* __restrict__ bias,
                                               int M, int K, int E) {
  __shared__ f16 lA[128 * 32];
  __shared__ f16 lB[128 * 32];
  int tid  = threadIdx.x;
  int lane = tid & 63;
  int wv   = __builtin_amdgcn_readfirstlane(tid >> 6);
  int nbe  = E >> 7;
  int bm = blockIdx.x / nbe, be = blockIdx.x % nbe;
  size_t m0 = (size_t)bm * 128, e0 = (size_t)be * 128;
  int wm = (wv & 1) * 64, we = (wv >> 1) * 64;
  int lm = lane & 15, q = lane >> 4;

  f32x4 acc[4][4] = {};

  int row_s[2], cg_s[2];
#pragma unroll
  for (int r = 0; r < 2; ++r) {
    int s = r * 256 + tid;
    row_s[r] = s >> 2;
    cg_s[r]  = (s & 3) ^ ((row_s[r] >> 1) & 3);
  }
  const f16* pa[4];
  const f16* pb[4];
#pragma unroll
  for (int i = 0; i < 4; ++i) {
    int ra = wm + i * 16 + lm;
    pa[i] = lA + ra * 32 + (q ^ ((ra >> 1) & 3)) * 8;
    int rb = we + i * 16 + lm;
    pb[i] = lB + rb * 32 + (q ^ ((rb >> 1) & 3)) * 8;
  }

  for (int k0 = 0; k0 < K; k0 += 32) {
#pragma unroll
    for (int r = 0; r < 2; ++r) {
      const f16* ga = A  + (m0 + row_s[r]) * K + k0 + cg_s[r] * 8;
      const f16* gb = Bt + (e0 + row_s[r]) * K + k0 + cg_s[r] * 8;
      async16(ga, lA + (r * 256 + wv * 64) * 8);
      async16(gb, lB + (r * 256 + wv * 64) * 8);
    }
    __syncthreads();
    f16x8 af[4], bf[4];
#pragma unroll
    for (int i = 0; i < 4; ++i) {
      af[i] = *(const f16x8*)pa[i];
      bf[i] = *(const f16x8*)pb[i];
    }
#pragma unroll
    for (int i = 0; i < 4; ++i)
#pragma unroll
      for (int j = 0; j < 4; ++j)
        acc[i][j] = __builtin_amdgcn_mfma_f32_16x16x32_f16(af[i], bf[j], acc[i][j], 0, 0, 0);
    __syncthreads();
  }

#pragma unroll
  for (int i = 0; i < 4; ++i) {
    size_t mbase = m0 + wm + i * 16 + q * 4;
#pragma unroll
    for (int j = 0; j < 4; ++j) {
      size_t e = e0 + we + j * 16 + lm;
#pragma unroll
      for (int g = 0; g < 4; ++g) {
        float val = acc[i][j][g];
        if (FP32OUT)
          ((float*)Cv)[(mbase + g) * (size_t)E + e] = val + bias[e];
        else
          ((f16*)Cv)[(mbase + g) * (size_t)E + e] = (f16)val;
      }
    }
  }
}

// ---------------- polar precompute (pair-of-d, vectorized I/O) ----------------
__global__ __launch_bounds__(256) void polar_kernel(const f16* __restrict__ qkv,
                                                    const float* __restrict__ freqs,
                                                    const float* __restrict__ fbias,
                                                    f16* __restrict__ Qp,
                                                    f16* __restrict__ Kp,
                                                    f16* __restrict__ Vt) {
  __shared__ f16 vt[64 * 66];
  int tid = threadIdx.x;
  int bx = blockIdx.x;
  int nt = bx & 15, bh = bx >> 4;
  int b = bh >> 4, h = bh & 15;
  size_t tok0 = (size_t)b * Nn + nt * 64;
  int n0 = nt * 64;
  constexpr float kScale = 0.125f;  // DH^-0.5 folded into Q
#pragma unroll
  for (int i = 0; i < 8; ++i) {
    int e2 = tid + i * 256;
    int nl = e2 >> 5, dp = (e2 & 31) * 2;
    size_t src = (tok0 + nl) * EQKV + h * 64 + dp;
    f16x2 q2 = *(const f16x2*)(qkv + src);
    f16x2 k2 = *(const f16x2*)(qkv + src + 1024);
    f16x2 v2 = *(const f16x2*)(qkv + src + 2048);
    int fidx = (n0 + nl) * 64 + dp;
    float2 f2  = *(const float2*)(freqs + fidx);
    float2 fb2 = *(const float2*)(fbias + fidx);
    f16x2 qc, qs, kc, ksn;
#pragma unroll
    for (int u = 0; u < 2; ++u) {
      float fq = u ? f2.y : f2.x;
      float fk = fq + (u ? fb2.y : fb2.x);
      float spq = softplusf((float)q2[u]) * kScale;
      float spk = softplusf((float)k2[u]);
      float snq, csq, snk, csk;
      __sincosf(fq, &snq, &csq);
      __sincosf(fk, &snk, &csk);
      qc[u]  = (f16)(spq * csq);
      qs[u]  = (f16)(spq * snq);
      kc[u]  = (f16)(spk * csk);
      ksn[u] = (f16)(spk * snk);
    }
    size_t dst = ((size_t)bh * Nn + n0 + nl) * 128 + dp;
    *(f16x2*)(Qp + dst)      = qc;
    *(f16x2*)(Qp + dst + 64) = qs;
    *(f16x2*)(Kp + dst)      = kc;
    *(f16x2*)(Kp + dst + 64) = ksn;
    vt[dp * 66 + nl]       = v2[0];
    vt[(dp + 1) * 66 + nl] = v2[1];
  }
  __syncthreads();
#pragma unroll
  for (int i = 0; i < 16; ++i) {
    int e = tid + i * 256;
    int d = e >> 6, nl = e & 63;
    Vt[((size_t)bh * 64 + d) * Nn + n0 + nl] = vt[d * 66 + nl];
  }
}

// ---------------- flash attention v5: 32 q-rows/wave + ones-row rowsum ----------------
// S^T = Kp·Qp^T (16x16x32); P feeds PV (16x16x16) straight from registers.
// Wave owns 32 q-rows (2 col-groups of 16): K/V LDS fragments loaded ONCE, reused by
// both groups -> per-row LDS traffic halves.  V^T tile is 80 rows: rows 0-63 = data
// (DMA), row 64 = 1.0, rows 65-79 = 0 (init once) -> PV's 5th tile accumulates the
// softmax row-sum with alpha-rescale for free; l extracted once in the epilogue.
// LDS: K dbuf 2x16 KB + V dbuf 2x10 KB = 52 KB -> 3 blocks/CU (12 waves).
constexpr int VK0 = 0;       // halfs
constexpr int VK1 = 8192;
constexpr int VV0 = 16384;   // 80*64 = 5120 halfs per buffer
constexpr int VV1 = 21504;
constexpr int VEND = 26624;

__global__ __launch_bounds__(256, 3) void attn_kernel(const f16* __restrict__ Qp,
                                                      const f16* __restrict__ Kp,
                                                      const f16* __restrict__ Vt,
                                                      f16* __restrict__ attout) {
  __shared__ f16 smem[VEND];  // 52 KB

  int tid = threadIdx.x, lane = tid & 63;
  int wv = __builtin_amdgcn_readfirstlane(tid >> 6);  // 0..3
  int lm = lane & 15, q = lane >> 4;
  int bx = blockIdx.x;
  int bh = (bx & 7) | ((bx >> 6) << 3);  // XCD swizzle: same head -> same bx%8
  int qt = (bx >> 3) & 7;                // 8 q-tiles of 128 rows
  const f16* Kbase = Kp + (size_t)bh * Nn * 128;
  const f16* Vbase = Vt + (size_t)bh * 64 * Nn;

  // ---- init V rows 64..79 (row 64 = ones, rest 0) in BOTH buffers, once ----
  {
    int idx = tid * 4;                 // 0..1020
    f16 val = (idx < 64) ? (f16)1.0f : (f16)0.0f;  // idx>>6==0 -> row 64
    f16x4 v4 = {val, val, val, val};
    *(f16x4*)(smem + VV0 + 64 * 64 + idx) = v4;
    *(f16x4*)(smem + VV1 + 64 * 64 + idx) = v4;
  }

  // ---- prologue: DMA K/V tile 0 ----
#pragma unroll
  for (int i = 0; i < 4; ++i) {
    int s = i * 256 + tid;
    int r = s >> 4, c = s & 15;
    int g = c ^ (r & 15);
    async16(Kbase + (size_t)r * 128 + g * 8, smem + VK0 + (i * 256 + wv * 64) * 8);
  }
#pragma unroll
  for (int i = 0; i < 2; ++i) {
    int s = i * 256 + tid;
    int r = s >> 3, c = s & 7;
    int g = c ^ (r & 7);
    async16(Vbase + (size_t)r * Nn + g * 8, smem + VV0 + (i * 256 + wv * 64) * 8);
  }

  // ---- Q frags: 32 rows/wave = 2 groups of 16 (B operand of S^T) ----
  f16x8 qf[2][4];
  {
    const f16* Qb = Qp + ((size_t)bh * Nn + qt * 128 + wv * 32) * 128;
#pragma unroll
    for (int grp = 0; grp < 2; ++grp)
#pragma unroll
      for (int ks = 0; ks < 4; ++ks)
        qf[grp][ks] = *(const f16x8*)(Qb + (size_t)(grp * 16 + lm) * 128 + ks * 32 + q * 8);
  }

  f32x4 O[2][5] = {};   // O^T per group; [.][4] row 0 = softmax denominator
  float mrow[2] = {-INFINITY, -INFINITY};

  for (int kt = 0; kt < 16; ++kt) {
    __syncthreads();  // tile kt ready (its DMA was issued a full compute-phase ago)

    if (kt < 15) {
      f16* nK = smem + ((kt & 1) ? VK0 : VK1);
      f16* nV = smem + ((kt & 1) ? VV0 : VV1);
#pragma unroll
      for (int i = 0; i < 4; ++i) {
        int s = i * 256 + tid;
        int r = s >> 4, c = s & 15;
        int g = c ^ (r & 15);
        async16(Kbase + (size_t)((kt + 1) * 64 + r) * 128 + g * 8, nK + (i * 256 + wv * 64) * 8);
      }
#pragma unroll
      for (int i = 0; i < 2; ++i) {
        int s = i * 256 + tid;
        int r = s >> 3, c = s & 7;
        int g = c ^ (r & 7);
        async16(Vbase + (size_t)r * Nn + (kt + 1) * 64 + g * 8, nV + (i * 256 + wv * 64) * 8);
      }
    }
    const f16* sK = smem + ((kt & 1) ? VK1 : VK0);
    const f16* sV = smem + ((kt & 1) ? VV1 : VV0);

    // ---- S^T = Kp * Qp^T (64 keys x 32 q-rows); kf loaded once per nt ----
    f32x4 S[2][4] = {};
#pragma unroll
    for (int nt = 0; nt < 4; ++nt) {
      f16x8 kf[4];
#pragma unroll
      for (int ks = 0; ks < 4; ++ks)
        kf[ks] = *(const f16x8*)(sK + (nt * 16 + lm) * 128 + (((ks * 4 + q) ^ lm) * 8));
#pragma unroll
      for (int ks = 0; ks < 4; ++ks) {
        S[0][nt] = __builtin_amdgcn_mfma_f32_16x16x32_f16(kf[ks], qf[0][ks], S[0][nt], 0, 0, 0);
        S[1][nt] = __builtin_amdgcn_mfma_f32_16x16x32_f16(kf[ks], qf[1][ks], S[1][nt], 0, 0, 0);
      }
    }

    // ---- online softmax per group (no rowsum: folded into PV ones-row) ----
    f16x4 pf[2][4];
#pragma unroll
    for (int grp = 0; grp < 2; ++grp) {
      float mx = -INFINITY;
#pragma unroll
      for (int nt = 0; nt < 4; ++nt)
#pragma unroll
        for (int g = 0; g < 4; ++g) mx = fmaxf(mx, S[grp][nt][g]);
      mx = fmaxf(mx, __shfl_xor(mx, 16, 64));
      mx = fmaxf(mx, __shfl_xor(mx, 32, 64));
      float mn = fmaxf(mrow[grp], mx);
      float alpha = __expf(mrow[grp] - mn);
      mrow[grp] = mn;
#pragma unroll
      for (int nt = 0; nt < 4; ++nt)
#pragma unroll
        for (int g = 0; g < 4; ++g)
          pf[grp][nt][g] = (f16)__expf(S[grp][nt][g] - mn);
#pragma unroll
      for (int nto = 0; nto < 5; ++nto)
#pragma unroll
        for (int g = 0; g < 4; ++g) O[grp][nto][g] *= alpha;
    }

    // ---- O^T += V^T * P^T ; vf loaded once per (nto,nt), reused by both groups ----
#pragma unroll
    for (int nto = 0; nto < 5; ++nto) {
      int r = nto * 16 + lm;
#pragma unroll
      for (int nt = 0; nt < 4; ++nt) {
        int c16 = (nt * 2 + (q >> 1)) ^ (r & 7);
        f16x4 vf = *(const f16x4*)(sV + r * 64 + c16 * 8 + (q & 1) * 4);
        O[0][nto] = __builtin_amdgcn_mfma_f32_16x16x16f16(vf, pf[0][nt], O[0][nto], 0, 0, 0);
        O[1][nto] = __builtin_amdgcn_mfma_f32_16x16x16f16(vf, pf[1][nt], O[1][nto], 0, 0, 0);
      }
    }
  }

  // ---- epilogue: l = O[grp][4][0] (d-row 64, lives in q==0 lanes), broadcast ----
  int b = bh >> 4, h = bh & 15;
#pragma unroll
  for (int grp = 0; grp < 2; ++grp) {
    float l = __shfl(O[grp][4][0], lm, 64);  // source lane lm (q==0) holds the rowsum
    float inv = 1.f / l;
    size_t token = (size_t)b * Nn + qt * 128 + wv * 32 + grp * 16 + lm;
#pragma unroll
    for (int nto = 0; nto < 4; ++nto) {
      f16x4 o4;
#pragma unroll
      for (int g = 0; g < 4; ++g) o4[g] = (f16)(O[grp][nto][g] * inv);
      *(f16x4*)(attout + token * (size_t)(Hh * DH) + h * 64 + nto * 16 + q * 4) = o4;
    }
  }
}

// ---------------- launch ----------------
extern "C" void kernel_launch(void* const* d_in, const int* in_sizes, int n_in,
                              void* d_out, int out_size, void* d_ws, size_t ws_size,
                              hipStream_t stream) {
  const float* x     = (const float*)d_in[0];
  const float* freqs = (const float*)d_in[1];
  const float* fbias = (const float*)d_in[2];
  const float* gamma = (const float*)d_in[3];
  const float* beta  = (const float*)d_in[4];
  const float* w_qk  = (const float*)d_in[5];
  const float* w_v   = (const float*)d_in[6];
  const float* w_out = (const float*)d_in[7];
  const float* b_out = (const float*)d_in[8];
  float* out = (float*)d_out;

  const size_t T = (size_t)Bb * Nn;  // 8192 tokens
  f16* WqkvT = (f16*)d_ws;                        // [3072][1024]
  f16* WoutT = WqkvT + (size_t)EQKV * DIM;        // [1024][1024]
  f16* Xn    = WoutT + (size_t)DIM * DIM;         // [8192][1024]
  f16* QKV   = Xn + T * DIM;                      // [8192][3072]
  f16* AttO  = QKV + T * EQKV;                    // [8192][1024]
  f16* Qp    = AttO + T * DIM;                    // [128][1024][128]
  f16* Kp    = Qp + (size_t)128 * Nn * 128;       // [128][1024][128]
  f16* Vt    = Kp + (size_t)128 * Nn * 128;       // [128][64][1024]

  transpose_cvt3<<<dim3(64, 32, 3), 256, 0, stream>>>(w_qk, w_v, w_out, WqkvT, WoutT);

  ln_kernel<<<(int)T, 256, 0, stream>>>(x, gamma, beta, Xn);

  gemm_bt<false><<<(int)(T / 128) * (EQKV / 128), 256, 0, stream>>>(
      Xn, WqkvT, (void*)QKV, nullptr, (int)T, DIM, EQKV);

  polar_kernel<<<Bb * Hh * (Nn / 64), 256, 0, stream>>>(QKV, freqs, fbias, Qp, Kp, Vt);

  attn_kernel<<<Bb * Hh * (Nn / 128), 256, 0, stream>>>(Qp, Kp, Vt, AttO);

  gemm_bt<true><<<(int)(T / 128) * (DIM / 128), 256, 0, stream>>>(
      AttO, WoutT, (void*)out, b_out, (int)T, DIM, DIM);
}